// Round 4
// baseline (5427.810 us; speedup 1.0000x reference)
//
#include <hip/hip_runtime.h>

// SCLSTM on MI355X — R8: R5's proven capacity config (256 blocks, 16-feature
// tiles, 64-VGPR weight set, 32-block groups) + the R7 schedule changes that
// never got a fair test: T14 split staging, counted barriers, lagged ring0.
//
// R7 post-mortem: __launch_bounds__(512,2) capped VGPRs at 128; wv[2][16]
// (128 VGPR) spilled to scratch -> MFMA loop read weights from scratch
// (VALUBusy 3.2, dur 2.8x). Capacity reverted; cap lifted to (512,1).
// R6 post-mortem: centralized spin targets = coherence DoS. Flag array kept.
//
// Dead code (verified R1-R3): s==0 forever => st==0, slot_info==tanh(sb[l]).
// Remaining: 2-layer LSTM B=64,T=512,H=512; layers pipelined on disjoint sets.
//
// Certification protocol (lagged): A stores ring0(t-1) at TOP of body(t),
// after the recurrent-staging vmcnt so the MALL ack drains free at S4(t);
// flags(t)=t+1 certify it; publisher stores prog=t meaning "h0(<=t-1)
// readable". B stages h0(tt) only when prog_up >= tt+1 (prefetch of h0(t+1)
// at body(t) waits prog_up >= t+2). Backpressure: A checks prog_down >= t-8
// before overwriting ring0 slot (t-1)&7; B trails ~2-3 steps so never binds.

typedef unsigned short ushort;
typedef unsigned int uint;
typedef unsigned long long u64;
using bfrag = __attribute__((ext_vector_type(8))) short;
using cfrag = __attribute__((ext_vector_type(4))) float;
using i4    = __attribute__((ext_vector_type(4))) int;

constexpr int NBLK = 256, NTHR = 512;
constexpr int Bsz = 64, Tt = 512, Hsz = 512;
constexpr int D0 = 8;                     // ring0 (A->B) depth
constexpr int DP = 2;                     // private recurrence ring depth

constexpr long long OUT_HT = (long long)Bsz * Tt * Hsz;
constexpr long long OUT_CT = OUT_HT + (long long)Bsz * 2 * Hsz;
constexpr long long OUT_ST = OUT_CT + (long long)Bsz * 2 * Hsz;

// ws layout (bytes)
constexpr int WS_SLOTS_A = 0;                                 // 4 grp x 32 x 16 ints
constexpr int WS_SLOTS_B = 8 * 1024;
constexpr int WS_PROG_A  = 16 * 1024;
constexpr int WS_PROG_B  = 17 * 1024;
constexpr int WS_XCC     = 18 * 1024;                         // 8 x 32 x 16 ints
constexpr int WS_RING0   = 64 * 1024;                         // D0 x 64 x 512 ushort
constexpr int WS_RING1   = WS_RING0 + D0 * Bsz * Hsz * 2;     // DP x ... (B private)
constexpr int WS_RINGA   = WS_RING1 + DP * Bsz * Hsz * 2;     // DP x ... (A private)
constexpr int WS_TOTAL   = WS_RINGA + DP * Bsz * Hsz * 2;

__global__ __launch_bounds__(256) void sclstm_init(float* __restrict__ ws,
                                                   float* __restrict__ out) {
    int i = blockIdx.x * blockDim.x + threadIdx.x, st = gridDim.x * blockDim.x;
    for (int k = i; k < WS_TOTAL / 4; k += st) ws[k] = 0.f;
    for (int k = i; k < Bsz * 128; k += st) out[OUT_ST + k] = 0.f;  // st == 0 always
}

__device__ __forceinline__ float sigm(float x) { return 1.f / (1.f + __expf(-x)); }
__device__ __forceinline__ float ftanh(float x) {
    float e = __expf(2.f * x);
    return 1.f - 2.f / (e + 1.f);
}
__device__ __forceinline__ ushort f2bf(float f) {
    unsigned u = __builtin_bit_cast(unsigned, f);
    u += 0x7FFFu + ((u >> 16) & 1u);
    return (ushort)(u >> 16);
}
__device__ __forceinline__ int aload(const int* p) {
    return __hip_atomic_load(p, __ATOMIC_RELAXED, __HIP_MEMORY_SCOPE_AGENT);
}
__device__ __forceinline__ int load_sc0(const int* p) {   // bypass L1, read own-XCD L2
    int v;
    asm volatile("global_load_dword %0, %1, off sc0\n\ts_waitcnt vmcnt(0)"
                 : "=v"(v) : "v"(p) : "memory");
    return v;
}
__device__ __forceinline__ void spin_agent(const int* p, int v) {
    int it = 0;
    while (aload(p) < v) {
        __builtin_amdgcn_s_sleep(1);
        if (((++it) & 1023) == 0)
            __builtin_amdgcn_fence(__ATOMIC_ACQUIRE, "agent");  // safety net only
    }
}
__device__ __forceinline__ void spin_f(const int* p, int v, int fast) {
    if (fast) {
        int it = 0;
        while (load_sc0(p) < v) {
            __builtin_amdgcn_s_sleep(1);
            if (((++it) & 63) == 0)
                __builtin_amdgcn_fence(__ATOMIC_ACQUIRE, "agent");  // safety net only
        }
    } else {
        spin_agent(p, v);
    }
}
__device__ __forceinline__ void st_flag(int* p, int v, int fast) {
    if (fast) __hip_atomic_store(p, v, __ATOMIC_RELAXED, __HIP_MEMORY_SCOPE_WORKGROUP);
    else      __hip_atomic_store(p, v, __ATOMIC_RELAXED, __HIP_MEMORY_SCOPE_AGENT);
}
__device__ __forceinline__ void st_h(ushort* p, ushort v, int fast) {
    if (fast) __hip_atomic_store(p, v, __ATOMIC_RELAXED, __HIP_MEMORY_SCOPE_WORKGROUP);
    else      __hip_atomic_store(p, v, __ATOMIC_RELAXED, __HIP_MEMORY_SCOPE_AGENT);
}
__device__ __forceinline__ bfrag pack2(u64 q0, u64 q1) {
    bfrag v;
    v[0]=(short)(ushort)(q0); v[1]=(short)(ushort)(q0 >> 16);
    v[2]=(short)(ushort)(q0 >> 32); v[3]=(short)(ushort)(q0 >> 48);
    v[4]=(short)(ushort)(q1); v[5]=(short)(ushort)(q1 >> 16);
    v[6]=(short)(ushort)(q1 >> 32); v[7]=(short)(ushort)(q1 >> 48);
    return v;
}
__device__ __forceinline__ bfrag packf(float4 a, float4 b) {
    bfrag v;
    v[0]=(short)f2bf(a.x); v[1]=(short)f2bf(a.y); v[2]=(short)f2bf(a.z); v[3]=(short)f2bf(a.w);
    v[4]=(short)f2bf(b.x); v[5]=(short)f2bf(b.y); v[6]=(short)f2bf(b.z); v[7]=(short)f2bf(b.w);
    return v;
}
// raw barriers with counted waits (rule 18: sched_barrier right after the waitcnt)
__device__ __forceinline__ void bar_lgkm() {    // LDS ordering only; VMEM stays in flight
    asm volatile("s_waitcnt lgkmcnt(0)" ::: "memory");
    __builtin_amdgcn_sched_barrier(0);
    __builtin_amdgcn_s_barrier();
}
__device__ __forceinline__ void bar_vm0() {     // full drain: certifies ring stores
    asm volatile("s_waitcnt vmcnt(0) lgkmcnt(0)" ::: "memory");
    __builtin_amdgcn_sched_barrier(0);
    __builtin_amdgcn_s_barrier();
}
__device__ __forceinline__ void bar_raw() {
    __builtin_amdgcn_s_barrier();
}

__global__ __launch_bounds__(NTHR, 1) void sclstm_main(
    const float* __restrict__ inputs,   // (B,T,512) fp32
    const float* __restrict__ gW,       // (2, 2048, 1024) fp32
    const float* __restrict__ gb,       // (2, 2048)
    const float* __restrict__ sbias,    // (2, 512)
    float* __restrict__ out,
    float* __restrict__ ws)
{
    __shared__ __attribute__((aligned(16))) ushort frag_lds[32 * 512]; // 32 ks x 1KB
    __shared__ float part_lds[64 * 17 * 2];   // [(lrow*17 + col)*2 + g]
    __shared__ int fast_sh;

    char* wsb = (char*)ws;
    const int tid = threadIdx.x, blk = blockIdx.x;
    const int setB = blk & 1;                  // 0: layer0 (producer), 1: layer1
    const int grp = (blk >> 1) & 3;            // batch tile
    const int myidx = blk >> 3;                // 0..31 feature tile within group
    const int L = setB;
    const int b0 = grp * 16, m0 = myidx * 16;

    int* slots     = (int*)(wsb + (setB ? WS_SLOTS_B : WS_SLOTS_A)) + grp * 32 * 16;
    int* prog_self = (int*)(wsb + (setB ? WS_PROG_B : WS_PROG_A)) + grp * 16;
    int* prog_up   = (int*)(wsb + WS_PROG_A) + grp * 16;   // B waits: h0 certified
    int* prog_down = (int*)(wsb + WS_PROG_B) + grp * 16;   // A ring0 backpressure
    ushort* ring0 = (ushort*)(wsb + WS_RING0);
    ushort* ring1 = (ushort*)(wsb + WS_RING1);
    ushort* ringA = (ushort*)(wsb + WS_RINGA);
    ushort* ring_own = setB ? ring1 : ringA;   // private recurrence ring (L2-local)

    const int lane = tid & 63, wave = tid >> 6;
    const int tau = wave & 3, g = wave >> 2;   // gate tile, K-half (512 each)
    const int q = lane >> 4, lm = lane & 15;

    // ---- one-time: weights -> A-fragments (16 ksteps) = 64 VGPRs ----
    bfrag wv[16];
    {
        const int grow = tau * 512 + m0 + lm;
        const float* wrow = gW + ((size_t)L * 2048 + grow) * 1024 + g * 512 + q * 8;
        #pragma unroll
        for (int j = 0; j < 16; ++j) {
            const float* src = wrow + j * 32;
            wv[j] = packf(*(const float4*)src, *(const float4*)(src + 4));
        }
    }
    // ---- cell constants (tid<256): feature mi, batch b3 ----
    const int mi = tid & 15, b3 = tid >> 4;    // valid for tid<256
    float bias4[4] = {0.f, 0.f, 0.f, 0.f};
    float slotc = 0.f, c = 0.f;
    float hn_hold = 0.f;                       // h(t-1) fp32 (B: deferred out store)
    uint  hq_hold = 0;                         // h(t-1) bf16 (A: deferred ring0 store)
    if (tid < 256) {
        #pragma unroll
        for (int tg = 0; tg < 4; ++tg) bias4[tg] = gb[L * 2048 + tg * 512 + m0 + mi];
        slotc = ftanh(sbias[L * 512 + m0 + mi]);
    }

    // ---- runtime check: is this sync group on one XCD? (agent fallback if not) ----
    int fast;
    {
        unsigned xcc = (unsigned)__builtin_amdgcn_s_getreg((31 << 11) | 20) & 0xFu; // HW_REG_XCC_ID
        int* xarr = (int*)(wsb + WS_XCC) + (setB * 4 + grp) * 32 * 16;
        if (tid == 0) {
            __hip_atomic_store(xarr + myidx * 16, (int)xcc + 1,
                               __ATOMIC_RELAXED, __HIP_MEMORY_SCOPE_AGENT);
            int ok = 1, ref = 0;
            for (int i = 0; i < 32; ++i) {
                int v;
                while ((v = aload(xarr + i * 16)) == 0) __builtin_amdgcn_s_sleep(2);
                if (i == 0) ref = v; else ok &= (v == ref);
            }
            fast_sh = ok;
        }
        __syncthreads();
        fast = fast_sh;
    }

    // ---- prologue: direct-stage non-recurrent rows 0..15 for t=0 ----
    if (setB) {
        if (tid == 0) spin_agent(prog_up, 1);   // h0(0) certified
        __syncthreads();
    }
    #pragma unroll
    for (int it = 0; it < 2; ++it) {
        const int r = wave * 2 + it;
        bfrag v;
        if (!setB) {
            const float* xs = inputs + ((size_t)(b0 + lm) * Tt + 0) * 512 + r * 32 + q * 8;
            v = packf(*(const float4*)xs, *(const float4*)(xs + 4));
        } else {
            const ushort* hs = ring0 + (b0 + lm) * 512 + r * 32 + q * 8;  // slot 0
            u64 q0 = __hip_atomic_load((const u64*)hs, __ATOMIC_RELAXED, __HIP_MEMORY_SCOPE_AGENT);
            u64 q1 = __hip_atomic_load((const u64*)(hs + 4), __ATOMIC_RELAXED, __HIP_MEMORY_SCOPE_AGENT);
            v = pack2(q0, q1);
        }
        *(bfrag*)&frag_lds[r * 512 + lane * 8] = v;
    }

    int cach_down = 0;          // A wave-lane0 shadow of prog_down (monotone)
    float4 pxa[3][2];           // A: x prefetch regs (waves 1..7, 3 rows x 32B)
    u64 phb[3][2];              // B: h0 prefetch regs

    for (int t = 0; t < Tt; ++t) {
        const int rsp = (t - 1) & (DP - 1), rsc = t & (DP - 1);

        // ======== TOP ========
        // recurrent staging rows 16..31 from own ring FIRST (the asm vmcnt(0)
        // must not wait on the deferred stores issued below).
        {
            const ushort* hb_ = ring_own + (size_t)rsp * (Bsz * Hsz) + (b0 + lm) * 512 + q * 8;
            const ushort* p0 = hb_ + wave * 32;
            const ushort* p1 = hb_ + (wave + 8) * 32;
            bfrag v0, v1;
            if (fast) {
                i4 w0, w1;
                asm volatile(
                    "global_load_dwordx4 %0, %2, off sc0\n\t"
                    "global_load_dwordx4 %1, %3, off sc0\n\t"
                    "s_waitcnt vmcnt(0)"
                    : "=&v"(w0), "=&v"(w1) : "v"(p0), "v"(p1) : "memory");
                v0 = __builtin_bit_cast(bfrag, w0);
                v1 = __builtin_bit_cast(bfrag, w1);
            } else {
                u64 a0 = __hip_atomic_load((const u64*)p0, __ATOMIC_RELAXED, __HIP_MEMORY_SCOPE_AGENT);
                u64 a1 = __hip_atomic_load((const u64*)(p0 + 4), __ATOMIC_RELAXED, __HIP_MEMORY_SCOPE_AGENT);
                u64 c0 = __hip_atomic_load((const u64*)p1, __ATOMIC_RELAXED, __HIP_MEMORY_SCOPE_AGENT);
                u64 c1 = __hip_atomic_load((const u64*)(p1 + 4), __ATOMIC_RELAXED, __HIP_MEMORY_SCOPE_AGENT);
                v0 = pack2(a0, a1); v1 = pack2(c0, c1);
            }
            *(bfrag*)&frag_lds[(16 + wave) * 512 + lane * 8] = v0;
            *(bfrag*)&frag_lds[(24 + wave) * 512 + lane * 8] = v1;
        }
        // deferred stores (acks drain free at S4): A ring0(t-1), B out(t-1)
        if (t > 0 && tid < 256) {
            if (!setB) {
                const int tgt = t - 8;                 // overwrites h0(t-9)
                if (tgt > 0 && lane == 0) {            // spin in lane0; wave reconverges
                    while (cach_down < tgt) {
                        __builtin_amdgcn_s_sleep(1);
                        cach_down = aload(prog_down);
                    }
                }
                ushort* rp = ring0 + (size_t)((t - 1) & (D0 - 1)) * (Bsz * Hsz)
                           + (b0 + b3) * 512 + m0 + mi;
                __hip_atomic_store(rp, (ushort)hq_hold, __ATOMIC_RELAXED, __HIP_MEMORY_SCOPE_AGENT);
            } else {
                out[((size_t)(b0 + b3) * Tt + (t - 1)) * Hsz + m0 + mi] = hn_hold;
            }
        }
        int pv_now = 0x7fffffff;
        if (setB && wave > 0 && t + 1 < Tt)
            pv_now = aload(prog_up);                   // non-blocking; used post-S1

        bar_lgkm();                                    // S1: frag ready (LDS only)

        // ======== post-S1: prefetch issue for t+1 (waves 1..7) ========
        if (wave > 0 && t + 1 < Tt) {
            if (setB && pv_now < t + 2) {
                if (lane == 0) spin_agent(prog_up, t + 2);   // wave reconverges
            }
            #pragma unroll
            for (int it = 0; it < 3; ++it) {
                const int r = wave - 1 + it * 7;
                if (r < 16) {
                    if (!setB) {
                        const float* xs = inputs + ((size_t)(b0 + lm) * Tt + (t + 1)) * 512 + r * 32 + q * 8;
                        pxa[it][0] = *(const float4*)xs;
                        pxa[it][1] = *(const float4*)(xs + 4);
                    } else {
                        const ushort* hs = ring0 + (size_t)((t + 1) & (D0 - 1)) * (Bsz * Hsz)
                                         + (b0 + lm) * 512 + r * 32 + q * 8;
                        phb[it][0] = __hip_atomic_load((const u64*)hs, __ATOMIC_RELAXED, __HIP_MEMORY_SCOPE_AGENT);
                        phb[it][1] = __hip_atomic_load((const u64*)(hs + 4), __ATOMIC_RELAXED, __HIP_MEMORY_SCOPE_AGENT);
                    }
                }
            }
            asm volatile("" ::: "memory");             // pin issue point
        }

        // ======== MFMA: 16 ksteps over this wave's K-half, 2 chains ========
        cfrag C0 = {0.f, 0.f, 0.f, 0.f}, C1 = {0.f, 0.f, 0.f, 0.f};
        #pragma unroll
        for (int j = 0; j < 16; j += 2) {
            bfrag Bf0 = *(const bfrag*)&frag_lds[(g * 16 + j) * 512 + lane * 8];
            C0 = __builtin_amdgcn_mfma_f32_16x16x32_bf16(wv[j], Bf0, C0, 0, 0, 0);
            bfrag Bf1 = *(const bfrag*)&frag_lds[(g * 16 + j + 1) * 512 + lane * 8];
            C1 = __builtin_amdgcn_mfma_f32_16x16x32_bf16(wv[j + 1], Bf1, C1, 0, 0, 0);
        }
        #pragma unroll
        for (int reg = 0; reg < 4; ++reg) {
            const int lrow = tau * 16 + q * 4 + reg;   // C row (m89 layout)
            part_lds[(lrow * 17 + lm) * 2 + g] = C0[reg] + C1[reg];
        }
        bar_lgkm();                                    // S2: partials ready (LDS only)

        // ======== cell update (waves 0..3): 1 feature x 1 batch each ========
        if (tid < 256) {
            float gs[4];
            #pragma unroll
            for (int tg = 0; tg < 4; ++tg) {
                float2 p = *(const float2*)&part_lds[((tg * 16 + mi) * 17 + b3) * 2];
                gs[tg] = p.x + p.y + bias4[tg];
            }
            float cn = sigm(gs[1]) * c + sigm(gs[0]) * ftanh(gs[3]) + slotc;
            float hn = sigm(gs[2]) * ftanh(cn);
            c = cn; hn_hold = hn;
            hq_hold = f2bf(hn);
            st_h(ring_own + (size_t)rsc * (Bsz * Hsz) + (b0 + b3) * 512 + m0 + mi,
                 (ushort)hq_hold, fast);
        }
        bar_vm0();                                     // S4: ring stores certified
        if (tid == 0) st_flag(&slots[myidx * 16], t + 1, fast);

        // ======== window: unpack prefetch (waves 1..7) || barrier detect (wave0) ====
        if (wave > 0) {
            if (t + 1 < Tt) {
                #pragma unroll
                for (int it = 0; it < 3; ++it) {
                    const int r = wave - 1 + it * 7;
                    if (r < 16) {
                        bfrag v = setB ? pack2(phb[it][0], phb[it][1])
                                       : packf(pxa[it][0], pxa[it][1]);
                        *(bfrag*)&frag_lds[r * 512 + lane * 8] = v;
                    }
                }
            }
        } else {
            if (lane < 32) spin_f(&slots[lane * 16], t + 1, fast);
            if (myidx == 0 && lane == 0)
                __hip_atomic_store(prog_self, setB ? t + 1 : t,
                                   __ATOMIC_RELAXED, __HIP_MEMORY_SCOPE_AGENT);
        }
        bar_raw();                                     // S5: rendezvous only
    }

    // ======== epilogue ========
    if (!setB) {
        // flush ring0(Tt-1), certify with one extra flag round, publish prog=Tt
        if (tid < 256) {
            const int tgt = Tt - 8;
            if (lane == 0) {
                while (cach_down < tgt) {
                    __builtin_amdgcn_s_sleep(1);
                    cach_down = aload(prog_down);
                }
            }
            ushort* rp = ring0 + (size_t)((Tt - 1) & (D0 - 1)) * (Bsz * Hsz)
                       + (b0 + b3) * 512 + m0 + mi;
            __hip_atomic_store(rp, (ushort)hq_hold, __ATOMIC_RELAXED, __HIP_MEMORY_SCOPE_AGENT);
        }
        bar_vm0();
        if (tid == 0) st_flag(&slots[myidx * 16], Tt + 1, fast);
        if (wave == 0 && lane < 32) spin_f(&slots[lane * 16], Tt + 1, fast);
        if (myidx == 0 && tid == 0)
            __hip_atomic_store(prog_self, Tt, __ATOMIC_RELAXED, __HIP_MEMORY_SCOPE_AGENT);
        if (tid < 256) {
            out[OUT_HT + (size_t)(b0 + b3) * 1024 + 0 * 512 + m0 + mi] = hn_hold;
            out[OUT_CT + (size_t)(b0 + b3) * 1024 + 0 * 512 + m0 + mi] = c;
        }
    } else {
        if (tid < 256) {
            out[((size_t)(b0 + b3) * Tt + (Tt - 1)) * Hsz + m0 + mi] = hn_hold;
            out[OUT_HT + (size_t)(b0 + b3) * 1024 + 512 + m0 + mi] = hn_hold;
            out[OUT_CT + (size_t)(b0 + b3) * 1024 + 512 + m0 + mi] = c;
        }
    }
}

extern "C" void kernel_launch(void* const* d_in, const int* in_sizes, int n_in,
                              void* d_out, int out_size, void* d_ws, size_t ws_size,
                              hipStream_t stream) {
    (void)in_sizes; (void)n_in; (void)out_size; (void)ws_size;
    const float* inputs = (const float*)d_in[0];
    const float* gW = (const float*)d_in[5];
    const float* gb = (const float*)d_in[6];
    const float* sbias = (const float*)d_in[8];
    float* out = (float*)d_out;
    float* ws = (float*)d_ws;

    hipLaunchKernelGGL(sclstm_init, dim3(256), dim3(256), 0, stream, ws, out);
    hipLaunchKernelGGL(sclstm_main, dim3(NBLK), dim3(NTHR), 0, stream,
                       inputs, gW, gb, sbias, out, ws);
}

// Round 5
// 5130.587 us; speedup vs baseline: 1.0579x; 1.0579x over previous
//
#include <hip/hip_runtime.h>

// SCLSTM on MI355X — R9: verbatim R5 base (1824us anchor) + ONE schedule change:
// waves 4-7 (idle during cell phase) prefetch next-step non-recurrent rows into
// registers at post-S2; window becomes a pure unpack. B guarded by a non-blocking
// prog_up poll (fallback = exact R5 spin+stage). Micro: launch_bounds(512,1) so
// prefetch regs don't spill (grid=256=#CU, occupancy unchanged); prog_down shadow.
//
// R8 post-mortem: R7/R8's protocol bundle (lagged publish, pre-MFMA pacing spin,
// raw barriers, TOP-deferred stores) = 3.0x regression with clean regs and
// identical bytes -> bundle unattributable; reverted wholesale. One change/round.
// R6 post-mortem: centralized spin targets = coherence DoS. Flag array kept.
//
// Dead code (verified R1-R3): s==0 forever => st==0, slot_info==tanh(sb[l]).
// Remaining: 2-layer LSTM B=64,T=512,H=512; layers pipelined on disjoint sets.

typedef unsigned short ushort;
typedef unsigned int uint;
typedef unsigned long long u64;
using bfrag = __attribute__((ext_vector_type(8))) short;
using cfrag = __attribute__((ext_vector_type(4))) float;
using i4    = __attribute__((ext_vector_type(4))) int;

constexpr int NBLK = 256, NTHR = 512;
constexpr int Bsz = 64, Tt = 512, Hsz = 512;
constexpr int D0 = 8;                     // ring0 (A->B) depth
constexpr int DP = 2;                     // private recurrence ring depth

constexpr long long OUT_HT = (long long)Bsz * Tt * Hsz;
constexpr long long OUT_CT = OUT_HT + (long long)Bsz * 2 * Hsz;
constexpr long long OUT_ST = OUT_CT + (long long)Bsz * 2 * Hsz;

// ws layout (bytes)
constexpr int WS_PROG_A = 16 * 1024;
constexpr int WS_PROG_B = 17 * 1024;
constexpr int WS_XCC    = 18 * 1024;                          // 8 x 32 x 16 ints
constexpr int WS_SLOTS_A = 40 * 1024;                         // 4 grp x 32 x 16 ints
constexpr int WS_SLOTS_B = 48 * 1024;
constexpr int WS_RING0  = 64 * 1024;                          // D0 x 64 x 512 ushort
constexpr int WS_RING1  = WS_RING0 + D0 * Bsz * Hsz * 2;      // DP x ... (B private)
constexpr int WS_RINGA  = WS_RING1 + DP * Bsz * Hsz * 2;      // DP x ... (A private)
constexpr int WS_TOTAL  = WS_RINGA + DP * Bsz * Hsz * 2;

__global__ __launch_bounds__(256) void sclstm_init(float* __restrict__ ws,
                                                   float* __restrict__ out) {
    int i = blockIdx.x * blockDim.x + threadIdx.x, st = gridDim.x * blockDim.x;
    for (int k = i; k < WS_TOTAL / 4; k += st) ws[k] = 0.f;
    for (int k = i; k < Bsz * 128; k += st) out[OUT_ST + k] = 0.f;  // st == 0 always
}

__device__ __forceinline__ float sigm(float x) { return 1.f / (1.f + __expf(-x)); }
__device__ __forceinline__ float ftanh(float x) {
    float e = __expf(2.f * x);
    return 1.f - 2.f / (e + 1.f);
}
__device__ __forceinline__ ushort f2bf(float f) {
    unsigned u = __builtin_bit_cast(unsigned, f);
    u += 0x7FFFu + ((u >> 16) & 1u);
    return (ushort)(u >> 16);
}
__device__ __forceinline__ int aload(const int* p) {
    return __hip_atomic_load(p, __ATOMIC_RELAXED, __HIP_MEMORY_SCOPE_AGENT);
}
__device__ __forceinline__ int load_sc0(const int* p) {   // bypass L1, read own-XCD L2
    int v;
    asm volatile("global_load_dword %0, %1, off sc0\n\ts_waitcnt vmcnt(0)"
                 : "=v"(v) : "v"(p) : "memory");
    return v;
}
__device__ __forceinline__ void spin_agent(const int* p, int v) {
    int it = 0;
    while (aload(p) < v) {
        __builtin_amdgcn_s_sleep(1);
        if (((++it) & 1023) == 0)
            __builtin_amdgcn_fence(__ATOMIC_ACQUIRE, "agent");  // safety net only
    }
}
__device__ __forceinline__ void spin_f(const int* p, int v, int fast) {
    if (fast) {
        int it = 0;
        while (load_sc0(p) < v) {
            __builtin_amdgcn_s_sleep(1);
            if (((++it) & 63) == 0)
                __builtin_amdgcn_fence(__ATOMIC_ACQUIRE, "agent");  // safety net only
        }
    } else {
        spin_agent(p, v);
    }
}
__device__ __forceinline__ void st_flag(int* p, int v, int fast) {
    if (fast) __hip_atomic_store(p, v, __ATOMIC_RELAXED, __HIP_MEMORY_SCOPE_WORKGROUP);
    else      __hip_atomic_store(p, v, __ATOMIC_RELAXED, __HIP_MEMORY_SCOPE_AGENT);
}
__device__ __forceinline__ void st_h(ushort* p, ushort v, int fast) {
    if (fast) __hip_atomic_store(p, v, __ATOMIC_RELAXED, __HIP_MEMORY_SCOPE_WORKGROUP);
    else      __hip_atomic_store(p, v, __ATOMIC_RELAXED, __HIP_MEMORY_SCOPE_AGENT);
}
__device__ __forceinline__ bfrag pack2(u64 q0, u64 q1) {
    bfrag v;
    v[0]=(short)(ushort)(q0); v[1]=(short)(ushort)(q0 >> 16);
    v[2]=(short)(ushort)(q0 >> 32); v[3]=(short)(ushort)(q0 >> 48);
    v[4]=(short)(ushort)(q1); v[5]=(short)(ushort)(q1 >> 16);
    v[6]=(short)(ushort)(q1 >> 32); v[7]=(short)(ushort)(q1 >> 48);
    return v;
}
__device__ __forceinline__ bfrag packf(float4 a, float4 b) {
    bfrag v;
    v[0]=(short)f2bf(a.x); v[1]=(short)f2bf(a.y); v[2]=(short)f2bf(a.z); v[3]=(short)f2bf(a.w);
    v[4]=(short)f2bf(b.x); v[5]=(short)f2bf(b.y); v[6]=(short)f2bf(b.z); v[7]=(short)f2bf(b.w);
    return v;
}

__global__ __launch_bounds__(NTHR, 1) void sclstm_main(
    const float* __restrict__ inputs,   // (B,T,512) fp32
    const float* __restrict__ gW,       // (2, 2048, 1024) fp32
    const float* __restrict__ gb,       // (2, 2048)
    const float* __restrict__ sbias,    // (2, 512)
    float* __restrict__ out,
    float* __restrict__ ws)
{
    __shared__ __attribute__((aligned(16))) ushort frag_lds[32 * 512]; // 32 ks x 1KB
    __shared__ float part_lds[64 * 17 * 2];   // [(lrow*17+col)*2 + g]
    __shared__ int fast_sh;

    char* wsb = (char*)ws;
    const int tid = threadIdx.x, blk = blockIdx.x;
    const int setB = blk & 1;                  // 0: layer0 (producer), 1: layer1
    const int grp = (blk >> 1) & 3;            // batch tile
    const int myidx = blk >> 3;                // 0..31 feature tile within group
    const int L = setB;
    const int b0 = grp * 16, m0 = myidx * 16;

    int* slots     = (int*)(wsb + (setB ? WS_SLOTS_B : WS_SLOTS_A)) + grp * 32 * 16;
    int* prog_self = (int*)(wsb + (setB ? WS_PROG_B : WS_PROG_A)) + grp * 16;
    int* prog_up   = (int*)(wsb + WS_PROG_A) + grp * 16;   // B waits: h0(t) ready
    int* prog_down = (int*)(wsb + WS_PROG_B) + grp * 16;   // A ring backpressure
    ushort* ring0 = (ushort*)(wsb + WS_RING0);
    ushort* ring1 = (ushort*)(wsb + WS_RING1);
    ushort* ringA = (ushort*)(wsb + WS_RINGA);
    ushort* ring_own = setB ? ring1 : ringA;   // private recurrence ring (L2-local)

    const int lane = tid & 63, wave = tid >> 6;
    const int tau = wave & 3, g = wave >> 2;   // gate tile, K-half (512 each)
    const int q = lane >> 4, lm = lane & 15;

    // ---- one-time: weights -> A-fragments (16 ksteps) = 64 VGPRs ----
    bfrag wv[16];
    {
        const int grow = tau * 512 + m0 + lm;
        const float* wrow = gW + ((size_t)L * 2048 + grow) * 1024 + g * 512 + q * 8;
        #pragma unroll
        for (int j = 0; j < 16; ++j) {
            const float* src = wrow + j * 32;
            wv[j] = packf(*(const float4*)src, *(const float4*)(src + 4));
        }
    }
    // ---- per-cell constants: 4 gate biases in regs, slot const, cell state ----
    float bias4[4] = {0.f, 0.f, 0.f, 0.f};
    float slotc = 0.f, c = 0.f;                // tid<256 = (mi=tid&15, b3=tid>>4)
    if (tid < 256) {
        const int mi = tid & 15;
        #pragma unroll
        for (int tg = 0; tg < 4; ++tg) bias4[tg] = gb[L * 2048 + tg * 512 + m0 + mi];
        slotc = ftanh(sbias[L * 512 + m0 + mi]);
    }

    // ---- runtime check: is this sync group on one XCD? (agent fallback if not) ----
    int fast;
    {
        unsigned xcc = (unsigned)__builtin_amdgcn_s_getreg((31 << 11) | 20) & 0xFu; // HW_REG_XCC_ID
        int* xarr = (int*)(wsb + WS_XCC) + (setB * 4 + grp) * 32 * 16;
        if (tid == 0) {
            __hip_atomic_store(xarr + myidx * 16, (int)xcc + 1,
                               __ATOMIC_RELAXED, __HIP_MEMORY_SCOPE_AGENT);
            int ok = 1, ref = 0;
            for (int i = 0; i < 32; ++i) {
                int v;
                while ((v = aload(xarr + i * 16)) == 0) __builtin_amdgcn_s_sleep(2);
                if (i == 0) ref = v; else ok &= (v == ref);
            }
            fast_sh = ok;
        }
        __syncthreads();
        fast = fast_sh;
    }

    // stage one non-recurrent row (ks = r in 0..15): A: x(tt); B: h0(tt) from ring0
    auto stage_row = [&](int r, int tt) {
        bfrag v;
        if (!setB) {
            const float* xs = inputs + ((size_t)(b0 + lm) * Tt + tt) * 512 + r * 32 + q * 8;
            v = packf(*(const float4*)xs, *(const float4*)(xs + 4));
        } else {
            const ushort* hs = ring0 + (size_t)(tt & (D0 - 1)) * (Bsz * Hsz)
                             + (b0 + lm) * 512 + r * 32 + q * 8;
            u64 q0 = __hip_atomic_load((const u64*)hs, __ATOMIC_RELAXED, __HIP_MEMORY_SCOPE_AGENT);
            u64 q1 = __hip_atomic_load((const u64*)(hs + 4), __ATOMIC_RELAXED, __HIP_MEMORY_SCOPE_AGENT);
            v = pack2(q0, q1);
        }
        *(bfrag*)&frag_lds[r * 512 + lane * 8] = v;
    };

    // ---- prologue: pre-stage non-recurrent half for t=0 (all 8 waves) ----
    if (setB) {
        if (tid == 0) spin_agent(prog_up, 1);
        __syncthreads();
    }
    stage_row(wave * 2, 0);
    stage_row(wave * 2 + 1, 0);

    int cach_down = 0;          // A wave0-lane0 shadow of prog_down (monotone)
    float4 pxa[4][2];           // A: x prefetch regs (waves 4-7: 4 rows x 32B)
    u64 phb[4][2];              // B: h0 prefetch regs

    for (int t = 0; t < Tt; ++t) {
        const int rsp = (t - 1) & (DP - 1), rsc = t & (DP - 1);

        // ---- recurrent staging rows 16..31 from own ring (all 8 waves) ----
        {
            const ushort* hb_ = ring_own + (size_t)rsp * (Bsz * Hsz) + (b0 + lm) * 512 + q * 8;
            const ushort* p0 = hb_ + wave * 32;          // kk = wave
            const ushort* p1 = hb_ + (wave + 8) * 32;    // kk = wave+8
            bfrag v0, v1;
            if (fast) {
                i4 w0, w1;
                asm volatile(
                    "global_load_dwordx4 %0, %2, off sc0\n\t"
                    "global_load_dwordx4 %1, %3, off sc0\n\t"
                    "s_waitcnt vmcnt(0)"
                    : "=&v"(w0), "=&v"(w1) : "v"(p0), "v"(p1) : "memory");
                v0 = __builtin_bit_cast(bfrag, w0);
                v1 = __builtin_bit_cast(bfrag, w1);
            } else {
                u64 a0 = __hip_atomic_load((const u64*)p0, __ATOMIC_RELAXED, __HIP_MEMORY_SCOPE_AGENT);
                u64 a1 = __hip_atomic_load((const u64*)(p0 + 4), __ATOMIC_RELAXED, __HIP_MEMORY_SCOPE_AGENT);
                u64 c0 = __hip_atomic_load((const u64*)p1, __ATOMIC_RELAXED, __HIP_MEMORY_SCOPE_AGENT);
                u64 c1 = __hip_atomic_load((const u64*)(p1 + 4), __ATOMIC_RELAXED, __HIP_MEMORY_SCOPE_AGENT);
                v0 = pack2(a0, a1); v1 = pack2(c0, c1);
            }
            *(bfrag*)&frag_lds[(16 + wave) * 512 + lane * 8] = v0;
            *(bfrag*)&frag_lds[(24 + wave) * 512 + lane * 8] = v1;
        }
        __syncthreads();                                  // S1: frag ready

        // ---- MFMA: 16 ksteps over this wave's K-half, 2 chains ----
        cfrag C0 = {0.f, 0.f, 0.f, 0.f}, C1 = {0.f, 0.f, 0.f, 0.f};
        #pragma unroll
        for (int j = 0; j < 16; j += 2) {
            bfrag Bf0 = *(const bfrag*)&frag_lds[(g * 16 + j) * 512 + lane * 8];
            C0 = __builtin_amdgcn_mfma_f32_16x16x32_bf16(wv[j], Bf0, C0, 0, 0, 0);
            bfrag Bf1 = *(const bfrag*)&frag_lds[(g * 16 + j + 1) * 512 + lane * 8];
            C1 = __builtin_amdgcn_mfma_f32_16x16x32_bf16(wv[j + 1], Bf1, C1, 0, 0, 0);
        }
        #pragma unroll
        for (int reg = 0; reg < 4; ++reg) {
            const int lrow = tau * 16 + q * 4 + reg;      // C row (m89 layout)
            part_lds[(lrow * 17 + lm) * 2 + g] = C0[reg] + C1[reg];
        }
        __syncthreads();                                  // S2: partials ready

        // ---- NEW: post-S2 prefetch (waves 4-7, idle during cell phase) ----
        // Issue next-step non-recurrent loads to regs; latency drains inside S4
        // concurrently with waves 0-3's store-acks. B: non-blocking guard poll
        // (same certification as R5's window guard); miss -> R5 fallback below.
        int havepf = 0;
        if (wave >= 4 && t + 1 < Tt) {
            if (!setB) {
                #pragma unroll
                for (int it = 0; it < 4; ++it) {
                    const int r = (wave - 4) * 4 + it;
                    const float* xs = inputs + ((size_t)(b0 + lm) * Tt + (t + 1)) * 512 + r * 32 + q * 8;
                    pxa[it][0] = *(const float4*)xs;
                    pxa[it][1] = *(const float4*)(xs + 4);
                }
                havepf = 1;
            } else if (aload(prog_up) >= t + 2) {
                #pragma unroll
                for (int it = 0; it < 4; ++it) {
                    const int r = (wave - 4) * 4 + it;
                    const ushort* hs = ring0 + (size_t)((t + 1) & (D0 - 1)) * (Bsz * Hsz)
                                     + (b0 + lm) * 512 + r * 32 + q * 8;
                    phb[it][0] = __hip_atomic_load((const u64*)hs, __ATOMIC_RELAXED, __HIP_MEMORY_SCOPE_AGENT);
                    phb[it][1] = __hip_atomic_load((const u64*)(hs + 4), __ATOMIC_RELAXED, __HIP_MEMORY_SCOPE_AGENT);
                }
                havepf = 1;
            }
        }

        // ---- cell update (waves 0-3): fused reduce + ring store ----
        float hn = 0.f, cn = 0.f;
        if (tid < 256) {
            const int mi = tid & 15, b3 = tid >> 4;
            float gs[4];
            #pragma unroll
            for (int tg = 0; tg < 4; ++tg) {
                float2 p = *(const float2*)&part_lds[((tg * 16 + mi) * 17 + b3) * 2];
                gs[tg] = p.x + p.y + bias4[tg];
            }
            cn = sigm(gs[1]) * c + sigm(gs[0]) * ftanh(gs[3]) + slotc;
            hn = sigm(gs[2]) * ftanh(cn);
            c = cn;
            const ushort hb16 = f2bf(hn);
            const size_t poff = (size_t)(b0 + b3) * 512 + m0 + mi;
            st_h(ring_own + (size_t)rsc * (Bsz * Hsz) + poff, hb16, fast);
            if (!setB)  // cross-XCD copy for layer 1 (agent scope)
                __hip_atomic_store(ring0 + (size_t)(t & (D0 - 1)) * (Bsz * Hsz) + poff,
                                   hb16, __ATOMIC_RELAXED, __HIP_MEMORY_SCOPE_AGENT);
        }
        __syncthreads();   // S4: drains ring stores AND prefetch loads per wave
        if (tid == 0)
            st_flag(&slots[myidx * 16], t + 1, fast);

        // ---- window: unpack prefetch (waves 4-7) / fallback stage; A backpressure --
        if (t + 1 < Tt) {
            if (wave >= 4) {
                if (havepf) {
                    #pragma unroll
                    for (int it = 0; it < 4; ++it) {
                        const int r = (wave - 4) * 4 + it;
                        bfrag v = setB ? pack2(phb[it][0], phb[it][1])
                                       : packf(pxa[it][0], pxa[it][1]);
                        *(bfrag*)&frag_lds[r * 512 + lane * 8] = v;
                    }
                } else {            // B prefetch miss: exact R5 behavior
                    spin_agent(prog_up, t + 2);   // uniform addr: 1 req/wave/poll
                    #pragma unroll
                    for (int it = 0; it < 4; ++it)
                        stage_row((wave - 4) * 4 + it, t + 1);
                }
            } else if (!setB && (t + 1) >= D0 && tid == 0) {
                const int tgt = t + 2 - D0;       // ring0 backpressure (shadowed)
                if (cach_down < tgt) {
                    cach_down = aload(prog_down);
                    while (cach_down < tgt) {
                        __builtin_amdgcn_s_sleep(1);
                        cach_down = aload(prog_down);
                    }
                }
            }
        }
        // ---- deferred output stores (overlap next phase; drained at S5) ----
        if (tid < 256) {
            const int mi = tid & 15, b3 = tid >> 4;
            if (setB)
                out[((size_t)(b0 + b3) * Tt + t) * Hsz + m0 + mi] = hn;
            if (t == Tt - 1) {
                out[OUT_HT + (size_t)(b0 + b3) * 1024 + L * 512 + m0 + mi] = hn;
                out[OUT_CT + (size_t)(b0 + b3) * 1024 + L * 512 + m0 + mi] = cn;
            }
        }
        if (tid < 32) spin_f(&slots[tid * 16], t + 1, fast);
        if (myidx == 0 && tid == 0)
            __hip_atomic_store(prog_self, t + 1,
                               __ATOMIC_RELAXED, __HIP_MEMORY_SCOPE_AGENT);
        __syncthreads();                                  // S5: barrier confirmed
    }
}

extern "C" void kernel_launch(void* const* d_in, const int* in_sizes, int n_in,
                              void* d_out, int out_size, void* d_ws, size_t ws_size,
                              hipStream_t stream) {
    (void)in_sizes; (void)n_in; (void)out_size; (void)ws_size;
    const float* inputs = (const float*)d_in[0];
    const float* gW = (const float*)d_in[5];
    const float* gb = (const float*)d_in[6];
    const float* sbias = (const float*)d_in[8];
    float* out = (float*)d_out;
    float* ws = (float*)d_ws;

    hipLaunchKernelGGL(sclstm_init, dim3(256), dim3(256), 0, stream, ws, out);
    hipLaunchKernelGGL(sclstm_main, dim3(NBLK), dim3(NTHR), 0, stream,
                       inputs, gW, gb, sbias, out, ws);
}

// Round 6
// 3021.964 us; speedup vs baseline: 1.7961x; 1.6978x over previous
//
#include <hip/hip_runtime.h>

// SCLSTM on MI355X — R10: verbatim R5 base (1824us anchor) + ONE traffic-neutral
// change: B's window spinner (tid==0, unchanged) captures the last prog_up value
// to LDS (pv_sh). Post-S1, guarded by pv_sh (block-uniform, no new flag reads),
// all 8 waves issue next-step non-recurrent loads to regs; S2's implicit vmcnt
// drain hides the MALL latency under MFMA; window becomes a reg->LDS unpack.
// Guard miss -> byte-exact R5 fallback.
//
// R9 post-mortem: R7/R8/R9 all ~5100us; common mode = MULTI-WAVE spinning/polling
// on prog_up (256 spinner waves on 4 MALL lines = sustained R6-style DoS; startup
// phase offset makes the guard miss persistently). Rule: exactly ONE thread per
// block may touch a cross-block flag — including "non-blocking" guard polls.
// R6 post-mortem: centralized spin targets = coherence DoS. Flag array kept.
//
// Dead code (verified R1-R3): s==0 forever => st==0, slot_info==tanh(sb[l]).
// Remaining: 2-layer LSTM B=64,T=512,H=512; layers pipelined on disjoint sets.

typedef unsigned short ushort;
typedef unsigned long long u64;
using bfrag = __attribute__((ext_vector_type(8))) short;
using cfrag = __attribute__((ext_vector_type(4))) float;
using i4    = __attribute__((ext_vector_type(4))) int;

constexpr int NBLK = 256, NTHR = 512;
constexpr int Bsz = 64, Tt = 512, Hsz = 512;
constexpr int D0 = 8;                     // ring0 (A->B) depth
constexpr int DP = 2;                     // private recurrence ring depth

constexpr long long OUT_HT = (long long)Bsz * Tt * Hsz;
constexpr long long OUT_CT = OUT_HT + (long long)Bsz * 2 * Hsz;
constexpr long long OUT_ST = OUT_CT + (long long)Bsz * 2 * Hsz;

// ws layout (bytes) — exact R5
constexpr int WS_SLOTS_A = 0;                                 // 4 grp x 32 x 16 ints
constexpr int WS_SLOTS_B = 8 * 1024;
constexpr int WS_PROG_A  = 16 * 1024;
constexpr int WS_PROG_B  = 17 * 1024;
constexpr int WS_XCC     = 18 * 1024;                         // 2 x 4 x 32 x 16 ints
constexpr int WS_RING0   = 64 * 1024;                         // D0 x 64 x 512 ushort
constexpr int WS_RING1   = WS_RING0 + D0 * Bsz * Hsz * 2;     // DP x ... (B private)
constexpr int WS_RINGA   = WS_RING1 + DP * Bsz * Hsz * 2;     // DP x ... (A private)
constexpr int WS_TOTAL   = WS_RINGA + DP * Bsz * Hsz * 2;

__global__ __launch_bounds__(256) void sclstm_init(float* __restrict__ ws,
                                                   float* __restrict__ out) {
    int i = blockIdx.x * blockDim.x + threadIdx.x, st = gridDim.x * blockDim.x;
    for (int k = i; k < WS_TOTAL / 4; k += st) ws[k] = 0.f;
    for (int k = i; k < Bsz * 128; k += st) out[OUT_ST + k] = 0.f;  // st == 0 always
}

__device__ __forceinline__ float sigm(float x) { return 1.f / (1.f + __expf(-x)); }
__device__ __forceinline__ float ftanh(float x) {
    float e = __expf(2.f * x);
    return 1.f - 2.f / (e + 1.f);
}
__device__ __forceinline__ ushort f2bf(float f) {
    unsigned u = __builtin_bit_cast(unsigned, f);
    u += 0x7FFFu + ((u >> 16) & 1u);
    return (ushort)(u >> 16);
}
__device__ __forceinline__ int aload(const int* p) {
    return __hip_atomic_load(p, __ATOMIC_RELAXED, __HIP_MEMORY_SCOPE_AGENT);
}
__device__ __forceinline__ int load_sc0(const int* p) {   // bypass L1, read own-XCD L2
    int v;
    asm volatile("global_load_dword %0, %1, off sc0\n\ts_waitcnt vmcnt(0)"
                 : "=v"(v) : "v"(p) : "memory");
    return v;
}
__device__ __forceinline__ void spin_agent(const int* p, int v) {
    int it = 0;
    while (aload(p) < v) {
        __builtin_amdgcn_s_sleep(1);
        if (((++it) & 1023) == 0)
            __builtin_amdgcn_fence(__ATOMIC_ACQUIRE, "agent");  // safety net only
    }
}
__device__ __forceinline__ int spin_cap(const int* p, int v) {   // returns last read
    int x = aload(p), it = 0;
    while (x < v) {
        __builtin_amdgcn_s_sleep(1);
        if (((++it) & 1023) == 0)
            __builtin_amdgcn_fence(__ATOMIC_ACQUIRE, "agent");  // safety net only
        x = aload(p);
    }
    return x;
}
__device__ __forceinline__ void spin_f(const int* p, int v, int fast) {
    if (fast) {
        int it = 0;
        while (load_sc0(p) < v) {
            __builtin_amdgcn_s_sleep(1);
            if (((++it) & 63) == 0)
                __builtin_amdgcn_fence(__ATOMIC_ACQUIRE, "agent");  // safety net only
        }
    } else {
        spin_agent(p, v);
    }
}
__device__ __forceinline__ void st_flag(int* p, int v, int fast) {
    if (fast) __hip_atomic_store(p, v, __ATOMIC_RELAXED, __HIP_MEMORY_SCOPE_WORKGROUP);
    else      __hip_atomic_store(p, v, __ATOMIC_RELAXED, __HIP_MEMORY_SCOPE_AGENT);
}
__device__ __forceinline__ void st_h(ushort* p, ushort v, int fast) {
    if (fast) __hip_atomic_store(p, v, __ATOMIC_RELAXED, __HIP_MEMORY_SCOPE_WORKGROUP);
    else      __hip_atomic_store(p, v, __ATOMIC_RELAXED, __HIP_MEMORY_SCOPE_AGENT);
}
__device__ __forceinline__ bfrag pack2(u64 q0, u64 q1) {
    bfrag v;
    v[0]=(short)(ushort)(q0); v[1]=(short)(ushort)(q0 >> 16);
    v[2]=(short)(ushort)(q0 >> 32); v[3]=(short)(ushort)(q0 >> 48);
    v[4]=(short)(ushort)(q1); v[5]=(short)(ushort)(q1 >> 16);
    v[6]=(short)(ushort)(q1 >> 32); v[7]=(short)(ushort)(q1 >> 48);
    return v;
}
__device__ __forceinline__ bfrag packf(float4 a, float4 b) {
    bfrag v;
    v[0]=(short)f2bf(a.x); v[1]=(short)f2bf(a.y); v[2]=(short)f2bf(a.z); v[3]=(short)f2bf(a.w);
    v[4]=(short)f2bf(b.x); v[5]=(short)f2bf(b.y); v[6]=(short)f2bf(b.z); v[7]=(short)f2bf(b.w);
    return v;
}

__global__ __launch_bounds__(NTHR, 2) void sclstm_main(
    const float* __restrict__ inputs,   // (B,T,512) fp32
    const float* __restrict__ gW,       // (2, 2048, 1024) fp32
    const float* __restrict__ gb,       // (2, 2048)
    const float* __restrict__ sbias,    // (2, 512)
    float* __restrict__ out,
    float* __restrict__ ws)
{
    __shared__ __attribute__((aligned(16))) ushort frag_lds[32 * 512]; // 32 ks x 1KB
    __shared__ float part_lds[64 * 17 * 2];   // [(lrow*17+col)*2 + g]
    __shared__ int fast_sh;
    __shared__ int pv_sh;                     // B: last observed prog_up (tid0-owned)

    char* wsb = (char*)ws;
    const int tid = threadIdx.x, blk = blockIdx.x;
    const int setB = blk & 1;                  // 0: layer0 (producer), 1: layer1
    const int grp = (blk >> 1) & 3;            // batch tile
    const int myidx = blk >> 3;                // 0..31 feature tile within group
    const int L = setB;
    const int b0 = grp * 16, m0 = myidx * 16;

    int* slots     = (int*)(wsb + (setB ? WS_SLOTS_B : WS_SLOTS_A)) + grp * 32 * 16;
    int* prog_self = (int*)(wsb + (setB ? WS_PROG_B : WS_PROG_A)) + grp * 16;
    int* prog_up   = (int*)(wsb + WS_PROG_A) + grp * 16;   // B waits: h0(t) ready
    int* prog_down = (int*)(wsb + WS_PROG_B) + grp * 16;   // A ring backpressure
    ushort* ring0 = (ushort*)(wsb + WS_RING0);
    ushort* ring1 = (ushort*)(wsb + WS_RING1);
    ushort* ringA = (ushort*)(wsb + WS_RINGA);
    ushort* ring_own = setB ? ring1 : ringA;   // private recurrence ring (L2-local)

    const int lane = tid & 63, wave = tid >> 6;
    const int tau = wave & 3, g = wave >> 2;   // gate tile, K-half (512 each)
    const int q = lane >> 4, lm = lane & 15;

    // ---- one-time: weights -> A-fragments (16 ksteps) = 64 VGPRs ----
    bfrag wv[16];
    {
        const int grow = tau * 512 + m0 + lm;
        const float* wrow = gW + ((size_t)L * 2048 + grow) * 1024 + g * 512 + q * 8;
        #pragma unroll
        for (int j = 0; j < 16; ++j) {
            const float* src = wrow + j * 32;
            wv[j] = packf(*(const float4*)src, *(const float4*)(src + 4));
        }
    }
    // ---- per-cell constants: 4 gate biases in regs, slot const, cell state ----
    float bias4[4] = {0.f, 0.f, 0.f, 0.f};
    float slotc = 0.f, c = 0.f;                // tid<256 = (mi=tid&15, b3=tid>>4)
    if (tid < 256) {
        const int mi = tid & 15;
        #pragma unroll
        for (int tg = 0; tg < 4; ++tg) bias4[tg] = gb[L * 2048 + tg * 512 + m0 + mi];
        slotc = ftanh(sbias[L * 512 + m0 + mi]);
    }

    // ---- runtime check: is this sync group on one XCD? (agent fallback if not) ----
    int fast;
    {
        unsigned xcc = (unsigned)__builtin_amdgcn_s_getreg((31 << 11) | 20) & 0xFu; // HW_REG_XCC_ID
        int* xarr = (int*)(wsb + WS_XCC) + (setB * 4 + grp) * 32 * 16;
        if (tid == 0) {
            __hip_atomic_store(xarr + myidx * 16, (int)xcc + 1,
                               __ATOMIC_RELAXED, __HIP_MEMORY_SCOPE_AGENT);
            int ok = 1, ref = 0;
            for (int i = 0; i < 32; ++i) {
                int v;
                while ((v = aload(xarr + i * 16)) == 0) __builtin_amdgcn_s_sleep(2);
                if (i == 0) ref = v; else ok &= (v == ref);
            }
            fast_sh = ok;
        }
        __syncthreads();
        fast = fast_sh;
    }

    // stage one non-recurrent row (ks = r in 0..15): A: x(tt); B: h0(tt) from ring0
    auto stage_row = [&](int r, int tt) {
        bfrag v;
        if (!setB) {
            const float* xs = inputs + ((size_t)(b0 + lm) * Tt + tt) * 512 + r * 32 + q * 8;
            v = packf(*(const float4*)xs, *(const float4*)(xs + 4));
        } else {
            const ushort* hs = ring0 + (size_t)(tt & (D0 - 1)) * (Bsz * Hsz)
                             + (b0 + lm) * 512 + r * 32 + q * 8;
            u64 q0 = __hip_atomic_load((const u64*)hs, __ATOMIC_RELAXED, __HIP_MEMORY_SCOPE_AGENT);
            u64 q1 = __hip_atomic_load((const u64*)(hs + 4), __ATOMIC_RELAXED, __HIP_MEMORY_SCOPE_AGENT);
            v = pack2(q0, q1);
        }
        *(bfrag*)&frag_lds[r * 512 + lane * 8] = v;
    };

    // ---- prologue: pre-stage non-recurrent half for t=0 (all 8 waves) ----
    if (setB) {
        if (tid == 0) pv_sh = spin_cap(prog_up, 1);
        __syncthreads();
    }
    stage_row(wave, 0);
    stage_row(wave + 8, 0);

    for (int t = 0; t < Tt; ++t) {
        const int rsp = (t - 1) & (DP - 1), rsc = t & (DP - 1);

        // ---- recurrent staging rows 16..31 from own ring (all 8 waves) ----
        {
            const ushort* hb_ = ring_own + (size_t)rsp * (Bsz * Hsz) + (b0 + lm) * 512 + q * 8;
            const ushort* p0 = hb_ + wave * 32;          // kk = wave
            const ushort* p1 = hb_ + (wave + 8) * 32;    // kk = wave+8
            bfrag v0, v1;
            if (fast) {
                i4 w0, w1;
                asm volatile(
                    "global_load_dwordx4 %0, %2, off sc0\n\t"
                    "global_load_dwordx4 %1, %3, off sc0\n\t"
                    "s_waitcnt vmcnt(0)"
                    : "=&v"(w0), "=&v"(w1) : "v"(p0), "v"(p1) : "memory");
                v0 = __builtin_bit_cast(bfrag, w0);
                v1 = __builtin_bit_cast(bfrag, w1);
            } else {
                u64 a0 = __hip_atomic_load((const u64*)p0, __ATOMIC_RELAXED, __HIP_MEMORY_SCOPE_AGENT);
                u64 a1 = __hip_atomic_load((const u64*)(p0 + 4), __ATOMIC_RELAXED, __HIP_MEMORY_SCOPE_AGENT);
                u64 c0 = __hip_atomic_load((const u64*)p1, __ATOMIC_RELAXED, __HIP_MEMORY_SCOPE_AGENT);
                u64 c1 = __hip_atomic_load((const u64*)(p1 + 4), __ATOMIC_RELAXED, __HIP_MEMORY_SCOPE_AGENT);
                v0 = pack2(a0, a1); v1 = pack2(c0, c1);
            }
            *(bfrag*)&frag_lds[(16 + wave) * 512 + lane * 8] = v0;
            *(bfrag*)&frag_lds[(24 + wave) * 512 + lane * 8] = v1;
        }
        __syncthreads();                                  // S1: frag ready

        // ---- NEW post-S1: guarded prefetch of next-step non-recurrent rows ----
        // Guard is the LDS-cached pv_sh (tid0-owned): NO cross-block reads here
        // except tid0's single refresh aload (latency drains free at S2).
        const int pf_ok = (t + 1 < Tt) && (!setB || pv_sh >= t + 2);
        float4 pxa[2][2];           // A: x(t+1) rows {wave, wave+8}
        u64 phb[2][2];              // B: h0(t+1) rows {wave, wave+8}
        int pv_new = 0;
        if (pf_ok) {
            if (setB && tid == 0) pv_new = aload(prog_up);   // refresh (non-blocking)
            #pragma unroll
            for (int it = 0; it < 2; ++it) {
                const int r = it * 8 + wave;
                if (!setB) {
                    const float* xs = inputs + ((size_t)(b0 + lm) * Tt + (t + 1)) * 512 + r * 32 + q * 8;
                    pxa[it][0] = *(const float4*)xs;
                    pxa[it][1] = *(const float4*)(xs + 4);
                } else {
                    const ushort* hs = ring0 + (size_t)((t + 1) & (D0 - 1)) * (Bsz * Hsz)
                                     + (b0 + lm) * 512 + r * 32 + q * 8;
                    phb[it][0] = __hip_atomic_load((const u64*)hs, __ATOMIC_RELAXED, __HIP_MEMORY_SCOPE_AGENT);
                    phb[it][1] = __hip_atomic_load((const u64*)(hs + 4), __ATOMIC_RELAXED, __HIP_MEMORY_SCOPE_AGENT);
                }
            }
            __builtin_amdgcn_sched_barrier(0);            // pin issue above MFMA
        }

        // ---- MFMA: 16 ksteps over this wave's K-half, 2 chains ----
        cfrag C0 = {0.f, 0.f, 0.f, 0.f}, C1 = {0.f, 0.f, 0.f, 0.f};
        #pragma unroll
        for (int j = 0; j < 16; j += 2) {
            bfrag Bf0 = *(const bfrag*)&frag_lds[(g * 16 + j) * 512 + lane * 8];
            C0 = __builtin_amdgcn_mfma_f32_16x16x32_bf16(wv[j], Bf0, C0, 0, 0, 0);
            bfrag Bf1 = *(const bfrag*)&frag_lds[(g * 16 + j + 1) * 512 + lane * 8];
            C1 = __builtin_amdgcn_mfma_f32_16x16x32_bf16(wv[j + 1], Bf1, C1, 0, 0, 0);
        }
        #pragma unroll
        for (int reg = 0; reg < 4; ++reg) {
            const int lrow = tau * 16 + q * 4 + reg;      // C row (m89 layout)
            part_lds[(lrow * 17 + lm) * 2 + g] = C0[reg] + C1[reg];
        }
        __syncthreads();                                  // S2: partials ready
                                                          // (drains prefetch vmcnt)

        // ---- cell update (waves 0-3): fused reduce + ring store ----
        float hn = 0.f, cn = 0.f;
        if (tid < 256) {
            const int mi = tid & 15, b3 = tid >> 4;
            float gs[4];
            #pragma unroll
            for (int tg = 0; tg < 4; ++tg) {
                float2 p = *(const float2*)&part_lds[((tg * 16 + mi) * 17 + b3) * 2];
                gs[tg] = p.x + p.y + bias4[tg];
            }
            cn = sigm(gs[1]) * c + sigm(gs[0]) * ftanh(gs[3]) + slotc;
            hn = sigm(gs[2]) * ftanh(cn);
            c = cn;
            const ushort hb16 = f2bf(hn);
            const size_t poff = (size_t)(b0 + b3) * 512 + m0 + mi;
            st_h(ring_own + (size_t)rsc * (Bsz * Hsz) + poff, hb16, fast);
            if (!setB)  // cross-XCD copy for layer 1 (agent scope)
                __hip_atomic_store(ring0 + (size_t)(t & (D0 - 1)) * (Bsz * Hsz) + poff,
                                   hb16, __ATOMIC_RELAXED, __HIP_MEMORY_SCOPE_AGENT);
        }
        __syncthreads();   // S4: drains vmcnt per wave: ring stores at LIC before flag
        if (tid == 0)
            st_flag(&slots[myidx * 16], t + 1, fast);

        // ---- window: unpack prefetch OR exact-R5 fallback; A backpressure ----
        if (t + 1 < Tt) {
            if (pf_ok) {
                if (tid == 0) {
                    if (setB) pv_sh = pv_new;              // publish refreshed view
                    else if ((t + 1) >= D0) spin_agent(prog_down, t + 2 - D0);
                }
                #pragma unroll
                for (int it = 0; it < 2; ++it) {
                    const int r = it * 8 + wave;
                    bfrag v = setB ? pack2(phb[it][0], phb[it][1])
                                   : packf(pxa[it][0], pxa[it][1]);
                    *(bfrag*)&frag_lds[r * 512 + lane * 8] = v;
                }
            } else {            // B only (pf_ok block-uniform): byte-exact R5 path
                if (tid == 0) pv_sh = spin_cap(prog_up, t + 2);
                __syncthreads();
                stage_row(wave, t + 1);
                stage_row(wave + 8, t + 1);
            }
        } else if (!setB && tid == 0) {
            // t == Tt-1: A has no stage; keep R5's (vacuous) backpressure position
        }
        // ---- deferred output stores (overlap next phase; drained at S5) ----
        if (tid < 256) {
            const int mi = tid & 15, b3 = tid >> 4;
            if (setB)
                out[((size_t)(b0 + b3) * Tt + t) * Hsz + m0 + mi] = hn;
            if (t == Tt - 1) {
                out[OUT_HT + (size_t)(b0 + b3) * 1024 + L * 512 + m0 + mi] = hn;
                out[OUT_CT + (size_t)(b0 + b3) * 1024 + L * 512 + m0 + mi] = cn;
            }
        }
        if (tid < 32) spin_f(&slots[tid * 16], t + 1, fast);
        if (myidx == 0 && tid == 0)
            __hip_atomic_store(prog_self, t + 1,
                               __ATOMIC_RELAXED, __HIP_MEMORY_SCOPE_AGENT);
        __syncthreads();                                  // S5: barrier confirmed
    }
}

extern "C" void kernel_launch(void* const* d_in, const int* in_sizes, int n_in,
                              void* d_out, int out_size, void* d_ws, size_t ws_size,
                              hipStream_t stream) {
    (void)in_sizes; (void)n_in; (void)out_size; (void)ws_size;
    const float* inputs = (const float*)d_in[0];
    const float* gW = (const float*)d_in[5];
    const float* gb = (const float*)d_in[6];
    const float* sbias = (const float*)d_in[8];
    float* out = (float*)d_out;
    float* ws = (float*)d_ws;

    hipLaunchKernelGGL(sclstm_init, dim3(256), dim3(256), 0, stream, ws, out);
    hipLaunchKernelGGL(sclstm_main, dim3(NBLK), dim3(NTHR), 0, stream,
                       inputs, gW, gb, sbias, out, ws);
}

// Round 7
// 2091.462 us; speedup vs baseline: 2.5952x; 1.4449x over previous
//
#include <hip/hip_runtime.h>

// SCLSTM on MI355X — R11: byte-equal R5 base (1824us anchor) + ONE strictly
// traffic-REDUCING change: tid0-register shadows for the two monotone cross-XCD
// progress flags. B's window spin on prog_up and A's backpressure spin on
// prog_down only issue a MALL read when the cached value is insufficient
// (~1 read per ~6 steps in steady state instead of every step). No scheduling,
// barrier, guard, or store changes — worst case is flat.
//
// R10 post-mortem: moving B's ring0 loads to post-S1 (latency hiding) regressed
// 1824->3022 with straggler profile. Combined with R7-R9: ANY re-scheduling of
// cross-XCD loads destabilizes the 8-group phase locking (shared-MALL feedback).
// Rule: don't move memory ops across the step schedule; only REMOVE traffic.
// R9 rule: exactly ONE thread per block touches a cross-block flag.
// R6 rule: never centralize spin targets.
//
// Dead code (verified R1-R3): s==0 forever => st==0, slot_info==tanh(sb[l]).
// Remaining: 2-layer LSTM B=64,T=512,H=512; layers pipelined on disjoint sets.

typedef unsigned short ushort;
typedef unsigned long long u64;
using bfrag = __attribute__((ext_vector_type(8))) short;
using cfrag = __attribute__((ext_vector_type(4))) float;
using i4    = __attribute__((ext_vector_type(4))) int;

constexpr int NBLK = 256, NTHR = 512;
constexpr int Bsz = 64, Tt = 512, Hsz = 512;
constexpr int D = 8;                      // h ring depth (steps), power of 2

constexpr long long OUT_HT = (long long)Bsz * Tt * Hsz;
constexpr long long OUT_CT = OUT_HT + (long long)Bsz * 2 * Hsz;
constexpr long long OUT_ST = OUT_CT + (long long)Bsz * 2 * Hsz;

// ws layout (bytes) — exact R5
constexpr int WS_SLOTS_A = 0;                               // 4 grp x 32 x 16 ints
constexpr int WS_SLOTS_B = 8 * 1024;
constexpr int WS_PROG_A  = 16 * 1024;
constexpr int WS_PROG_B  = 17 * 1024;
constexpr int WS_XCC     = 18 * 1024;                       // 2 x 4 x 32 x 16 ints
constexpr int WS_RING0   = 64 * 1024;                       // D x 64 x 512 ushort
constexpr int WS_RING1   = WS_RING0 + D * Bsz * Hsz * 2;    // DP x ... (B private)
constexpr int WS_RINGA   = WS_RING1 + 2 * Bsz * Hsz * 2;    // DP x ... (A private)
constexpr int WS_TOTAL   = WS_RINGA + 2 * Bsz * Hsz * 2;
constexpr int DP = 2;                     // private recurrence ring depth

__global__ __launch_bounds__(256) void sclstm_init(float* __restrict__ ws,
                                                   float* __restrict__ out) {
    int i = blockIdx.x * blockDim.x + threadIdx.x, st = gridDim.x * blockDim.x;
    for (int k = i; k < WS_TOTAL / 4; k += st) ws[k] = 0.f;
    for (int k = i; k < Bsz * 128; k += st) out[OUT_ST + k] = 0.f;  // st == 0 always
}

__device__ __forceinline__ float sigm(float x) { return 1.f / (1.f + __expf(-x)); }
__device__ __forceinline__ float ftanh(float x) {
    float e = __expf(2.f * x);
    return 1.f - 2.f / (e + 1.f);
}
__device__ __forceinline__ ushort f2bf(float f) {
    unsigned u = __builtin_bit_cast(unsigned, f);
    u += 0x7FFFu + ((u >> 16) & 1u);
    return (ushort)(u >> 16);
}
__device__ __forceinline__ int aload(const int* p) {
    return __hip_atomic_load(p, __ATOMIC_RELAXED, __HIP_MEMORY_SCOPE_AGENT);
}
__device__ __forceinline__ int load_sc0(const int* p) {   // bypass L1, read own-XCD L2
    int v;
    asm volatile("global_load_dword %0, %1, off sc0\n\ts_waitcnt vmcnt(0)"
                 : "=v"(v) : "v"(p) : "memory");
    return v;
}
__device__ __forceinline__ void spin_agent(const int* p, int v) {
    int it = 0;
    while (aload(p) < v) {
        __builtin_amdgcn_s_sleep(1);
        if (((++it) & 1023) == 0)
            __builtin_amdgcn_fence(__ATOMIC_ACQUIRE, "agent");  // safety net only
    }
}
__device__ __forceinline__ int spin_cap(const int* p, int v) {   // returns last read
    int x = aload(p), it = 0;
    while (x < v) {
        __builtin_amdgcn_s_sleep(1);
        if (((++it) & 1023) == 0)
            __builtin_amdgcn_fence(__ATOMIC_ACQUIRE, "agent");  // safety net only
        x = aload(p);
    }
    return x;
}
__device__ __forceinline__ void spin_f(const int* p, int v, int fast) {
    if (fast) {
        int it = 0;
        while (load_sc0(p) < v) {
            __builtin_amdgcn_s_sleep(1);
            if (((++it) & 63) == 0)
                __builtin_amdgcn_fence(__ATOMIC_ACQUIRE, "agent");  // safety net only
        }
    } else {
        spin_agent(p, v);
    }
}
__device__ __forceinline__ void st_flag(int* p, int v, int fast) {
    if (fast) __hip_atomic_store(p, v, __ATOMIC_RELAXED, __HIP_MEMORY_SCOPE_WORKGROUP);
    else      __hip_atomic_store(p, v, __ATOMIC_RELAXED, __HIP_MEMORY_SCOPE_AGENT);
}
__device__ __forceinline__ void st_h(ushort* p, ushort v, int fast) {
    if (fast) __hip_atomic_store(p, v, __ATOMIC_RELAXED, __HIP_MEMORY_SCOPE_WORKGROUP);
    else      __hip_atomic_store(p, v, __ATOMIC_RELAXED, __HIP_MEMORY_SCOPE_AGENT);
}
__device__ __forceinline__ bfrag pack2(u64 q0, u64 q1) {
    bfrag v;
    v[0]=(short)(ushort)(q0); v[1]=(short)(ushort)(q0 >> 16);
    v[2]=(short)(ushort)(q0 >> 32); v[3]=(short)(ushort)(q0 >> 48);
    v[4]=(short)(ushort)(q1); v[5]=(short)(ushort)(q1 >> 16);
    v[6]=(short)(ushort)(q1 >> 32); v[7]=(short)(ushort)(q1 >> 48);
    return v;
}

__global__ __launch_bounds__(NTHR, 2) void sclstm_main(
    const float* __restrict__ inputs,   // (B,T,512) fp32
    const float* __restrict__ gW,       // (2, 2048, 1024) fp32
    const float* __restrict__ gb,       // (2, 2048)
    const float* __restrict__ sbias,    // (2, 512)
    float* __restrict__ out,
    float* __restrict__ ws)
{
    __shared__ __attribute__((aligned(16))) ushort frag_lds[32 * 512]; // 32 ks x 1KB
    __shared__ float part_lds[64 * 17 * 2];   // [(lrow*17+col)*2 + g]
    __shared__ int fast_sh;

    char* wsb = (char*)ws;
    const int tid = threadIdx.x, blk = blockIdx.x;
    const int setB = blk & 1;                  // 0: layer0 (producer), 1: layer1
    const int grp = (blk >> 1) & 3;            // batch tile
    const int myidx = blk >> 3;                // 0..31 feature tile within group
    const int L = setB;
    const int b0 = grp * 16, m0 = myidx * 16;

    int* slots     = (int*)(wsb + (setB ? WS_SLOTS_B : WS_SLOTS_A)) + grp * 32 * 16;
    int* prog_self = (int*)(wsb + (setB ? WS_PROG_B : WS_PROG_A)) + grp * 16;
    int* prog_up   = (int*)(wsb + WS_PROG_A) + grp * 16;   // B waits: h0(t) ready
    int* prog_down = (int*)(wsb + WS_PROG_B) + grp * 16;   // A ring backpressure
    ushort* ring0 = (ushort*)(wsb + WS_RING0);
    ushort* ring1 = (ushort*)(wsb + WS_RING1);
    ushort* ringA = (ushort*)(wsb + WS_RINGA);
    ushort* ring_rec = setB ? ring1 : ringA;   // own recurrence ring (L2-local)

    const int lane = tid & 63, wave = tid >> 6;
    const int tau = wave & 3, g = wave >> 2;   // gate tile, K-half (512 each)
    const int q = lane >> 4, lm = lane & 15;

    // ---- one-time: weights -> A-fragments (one layer, 16 ksteps) = 64 VGPRs ----
    bfrag wv[16];
    {
        const int grow = tau * 512 + m0 + lm;
        const float* wrow = gW + ((size_t)L * 2048 + grow) * 1024 + g * 512 + q * 8;
        #pragma unroll
        for (int j = 0; j < 16; ++j) {
            const float* src = wrow + j * 32;
            float4 a = *(const float4*)src, b = *(const float4*)(src + 4);
            bfrag v;
            v[0]=(short)f2bf(a.x); v[1]=(short)f2bf(a.y); v[2]=(short)f2bf(a.z); v[3]=(short)f2bf(a.w);
            v[4]=(short)f2bf(b.x); v[5]=(short)f2bf(b.y); v[6]=(short)f2bf(b.z); v[7]=(short)f2bf(b.w);
            wv[j] = v;
        }
    }
    // ---- per-cell constants: 4 gate biases in regs, slot const, cell state ----
    float bias4[4] = {0.f, 0.f, 0.f, 0.f};
    float slotc = 0.f, c = 0.f;                // tid<256 = (mi=tid&15, b3=tid>>4)
    if (tid < 256) {
        const int mi = tid & 15;
        #pragma unroll
        for (int tg = 0; tg < 4; ++tg) bias4[tg] = gb[L * 2048 + tg * 512 + m0 + mi];
        slotc = ftanh(sbias[L * 512 + m0 + mi]);
    }

    // ---- runtime check: is this sync group on one XCD? (agent fallback if not) ----
    int fast;
    {
        unsigned xcc = (unsigned)__builtin_amdgcn_s_getreg((31 << 11) | 20) & 0xFu; // HW_REG_XCC_ID
        int* xarr = (int*)(wsb + WS_XCC) + (setB * 4 + grp) * 32 * 16;
        if (tid == 0) {
            __hip_atomic_store(xarr + myidx * 16, (int)xcc + 1,
                               __ATOMIC_RELAXED, __HIP_MEMORY_SCOPE_AGENT);
            int ok = 1, ref = 0;
            for (int i = 0; i < 32; ++i) {
                int v;
                while ((v = aload(xarr + i * 16)) == 0) __builtin_amdgcn_s_sleep(2);
                if (i == 0) ref = v; else ok &= (v == ref);
            }
            fast_sh = ok;
        }
        __syncthreads();
        fast = fast_sh;
    }

    // stage the non-recurrent K-half (rows 0..15): A: x(tt); B: h0(tt) from ring0
    auto stage_nonrec = [&](int tt) {
        #pragma unroll
        for (int it = 0; it < 2; ++it) {
            const int ks = it * 8 + wave;      // 0..15
            bfrag v;
            if (!setB) {
                const float* xs = inputs + ((size_t)(b0 + lm) * Tt + tt) * 512 + ks * 32 + q * 8;
                float4 a = *(const float4*)xs, b = *(const float4*)(xs + 4);
                v[0]=(short)f2bf(a.x); v[1]=(short)f2bf(a.y); v[2]=(short)f2bf(a.z); v[3]=(short)f2bf(a.w);
                v[4]=(short)f2bf(b.x); v[5]=(short)f2bf(b.y); v[6]=(short)f2bf(b.z); v[7]=(short)f2bf(b.w);
            } else {
                const ushort* hs = ring0 + (size_t)(tt & (D - 1)) * (Bsz * Hsz)
                                 + (b0 + lm) * 512 + ks * 32 + q * 8;
                u64 q0 = __hip_atomic_load((const u64*)hs, __ATOMIC_RELAXED, __HIP_MEMORY_SCOPE_AGENT);
                u64 q1 = __hip_atomic_load((const u64*)(hs + 4), __ATOMIC_RELAXED, __HIP_MEMORY_SCOPE_AGENT);
                v = pack2(q0, q1);
            }
            *(bfrag*)&frag_lds[ks * 512 + lane * 8] = v;
        }
    };

    // tid0-only monotone flag shadows (the R11 change)
    int pv_reg = 0;             // B: last observed prog_up
    int pd_reg = 0;             // A: last observed prog_down

    // ---- prologue: pre-stage non-recurrent half for t=0 ----
    if (setB) {
        if (tid == 0) pv_reg = spin_cap(prog_up, 1);
        __syncthreads();
    }
    stage_nonrec(0);

    for (int t = 0; t < Tt; ++t) {
        const int rsp = (t - 1) & (DP - 1), rsc = t & (DP - 1);

        // ---- recurrent staging (rows 16..31) from own ring ----
        {
            const ushort* hb_ = ring_rec + (size_t)rsp * (Bsz * Hsz) + (b0 + lm) * 512 + q * 8;
            const ushort* p0 = hb_ + wave * 32;          // kk = wave
            const ushort* p1 = hb_ + (wave + 8) * 32;    // kk = wave+8
            bfrag v0, v1;
            if (fast) {
                i4 w0, w1;
                asm volatile(
                    "global_load_dwordx4 %0, %2, off sc0\n\t"
                    "global_load_dwordx4 %1, %3, off sc0\n\t"
                    "s_waitcnt vmcnt(0)"
                    : "=&v"(w0), "=&v"(w1) : "v"(p0), "v"(p1) : "memory");
                v0 = __builtin_bit_cast(bfrag, w0);
                v1 = __builtin_bit_cast(bfrag, w1);
            } else {
                u64 a0 = __hip_atomic_load((const u64*)p0, __ATOMIC_RELAXED, __HIP_MEMORY_SCOPE_AGENT);
                u64 a1 = __hip_atomic_load((const u64*)(p0 + 4), __ATOMIC_RELAXED, __HIP_MEMORY_SCOPE_AGENT);
                u64 c0 = __hip_atomic_load((const u64*)p1, __ATOMIC_RELAXED, __HIP_MEMORY_SCOPE_AGENT);
                u64 c1 = __hip_atomic_load((const u64*)(p1 + 4), __ATOMIC_RELAXED, __HIP_MEMORY_SCOPE_AGENT);
                v0 = pack2(a0, a1); v1 = pack2(c0, c1);
            }
            *(bfrag*)&frag_lds[(16 + wave) * 512 + lane * 8] = v0;
            *(bfrag*)&frag_lds[(24 + wave) * 512 + lane * 8] = v1;
        }
        __syncthreads();                                  // S1: frag ready

        // ---- MFMA: 16 ksteps over this wave's K-half, 2 chains ----
        cfrag C0 = {0.f, 0.f, 0.f, 0.f}, C1 = {0.f, 0.f, 0.f, 0.f};
        #pragma unroll
        for (int j = 0; j < 16; j += 2) {
            bfrag Bf0 = *(const bfrag*)&frag_lds[(g * 16 + j) * 512 + lane * 8];
            C0 = __builtin_amdgcn_mfma_f32_16x16x32_bf16(wv[j], Bf0, C0, 0, 0, 0);
            bfrag Bf1 = *(const bfrag*)&frag_lds[(g * 16 + j + 1) * 512 + lane * 8];
            C1 = __builtin_amdgcn_mfma_f32_16x16x32_bf16(wv[j + 1], Bf1, C1, 0, 0, 0);
        }
        #pragma unroll
        for (int reg = 0; reg < 4; ++reg) {
            const int lrow = tau * 16 + q * 4 + reg;      // C row (m89 layout)
            part_lds[(lrow * 17 + lm) * 2 + g] = C0[reg] + C1[reg];
        }
        __syncthreads();                                  // S2: partials ready

        // ---- cell update: fused reduce + ring store ----
        float hn = 0.f, cn = 0.f;
        if (tid < 256) {
            const int mi = tid & 15, b3 = tid >> 4;
            float gs[4];
            #pragma unroll
            for (int tg = 0; tg < 4; ++tg) {
                float2 p = *(const float2*)&part_lds[((tg * 16 + mi) * 17 + b3) * 2];
                gs[tg] = p.x + p.y + bias4[tg];
            }
            cn = sigm(gs[1]) * c + sigm(gs[0]) * ftanh(gs[3]) + slotc;
            hn = sigm(gs[2]) * ftanh(cn);
            c = cn;
            const ushort hb16 = f2bf(hn);
            const size_t poff = (size_t)(b0 + b3) * 512 + m0 + mi;
            st_h(ring_rec + (size_t)rsc * (Bsz * Hsz) + poff, hb16, fast);
            if (!setB)  // cross-XCD copy for layer 1 (agent scope)
                __hip_atomic_store(ring0 + (size_t)(t & (D - 1)) * (Bsz * Hsz) + poff,
                                   hb16, __ATOMIC_RELAXED, __HIP_MEMORY_SCOPE_AGENT);
        }
        __syncthreads();   // S4: drains vmcnt per wave: ring stores at LIC before flag
        if (tid == 0)
            st_flag(&slots[myidx * 16], t + 1, fast);

        // ---- window: stage t+1 (R5 schedule; flag reads now shadow-gated) ----
        if (t + 1 < Tt) {
            if (setB) {
                if (tid == 0 && pv_reg < t + 2)
                    pv_reg = spin_cap(prog_up, t + 2);     // only when shadow stale
                __syncthreads();
                stage_nonrec(t + 1);
            } else {
                if ((t + 1) >= D && tid == 0) {
                    const int tgt = t + 2 - D;             // ring0 backpressure
                    if (pd_reg < tgt)
                        pd_reg = spin_cap(prog_down, tgt); // only when shadow stale
                }
                stage_nonrec(t + 1);
            }
        }
        // ---- deferred output stores (overlap next phase; drained at S5) ----
        if (tid < 256) {
            const int mi = tid & 15, b3 = tid >> 4;
            if (setB)
                out[((size_t)(b0 + b3) * Tt + t) * Hsz + m0 + mi] = hn;
            if (t == Tt - 1) {
                out[OUT_HT + (size_t)(b0 + b3) * 1024 + L * 512 + m0 + mi] = hn;
                out[OUT_CT + (size_t)(b0 + b3) * 1024 + L * 512 + m0 + mi] = cn;
            }
        }
        if (tid < 32) spin_f(&slots[tid * 16], t + 1, fast);
        if (myidx == 0 && tid == 0)
            __hip_atomic_store(prog_self, t + 1,
                               __ATOMIC_RELAXED, __HIP_MEMORY_SCOPE_AGENT);
        __syncthreads();                                  // S5: barrier confirmed
    }
}

extern "C" void kernel_launch(void* const* d_in, const int* in_sizes, int n_in,
                              void* d_out, int out_size, void* d_ws, size_t ws_size,
                              hipStream_t stream) {
    (void)in_sizes; (void)n_in; (void)out_size; (void)ws_size;
    const float* inputs = (const float*)d_in[0];
    const float* gW = (const float*)d_in[5];
    const float* gb = (const float*)d_in[6];
    const float* sbias = (const float*)d_in[8];
    float* out = (float*)d_out;
    float* ws = (float*)d_ws;

    hipLaunchKernelGGL(sclstm_init, dim3(256), dim3(256), 0, stream, ws, out);
    hipLaunchKernelGGL(sclstm_main, dim3(NBLK), dim3(NTHR), 0, stream,
                       inputs, gW, gb, sbias, out, ws);
}